// Round 10
// baseline (1538.574 us; speedup 1.0000x reference)
//
#include <hip/hip_runtime.h>
#include <stdint.h>
#include <stddef.h>

#define BB 64
#define LL 196
#define FF 2048
#define HH 512
#define VV 9488
#define NPAD 9600        // lWb padded rows (75 x 128); pad rows stay finite poison
#define TT 16
#define KXX 3072         // H + F + H
#define MM (BB * LL)     // 12544

typedef short short8 __attribute__((ext_vector_type(8)));
typedef float f32x4 __attribute__((ext_vector_type(4)));
typedef unsigned short u16;

__device__ __forceinline__ u16 f2bf(float f) {
  uint32_t u = __builtin_bit_cast(uint32_t, f);
  u += 0x7FFFu + ((u >> 16) & 1u);   // RNE
  return (u16)(u >> 16);
}
__device__ __forceinline__ float bf2f(u16 s) {
  return __builtin_bit_cast(float, ((uint32_t)s) << 16);
}
__device__ __forceinline__ float fast_tanh(float x) {
  return 1.0f - 2.0f / (1.0f + __expf(2.0f * x));
}
__device__ __forceinline__ float fast_sig(float x) {
  return 1.0f / (1.0f + __expf(-x));
}
__device__ __forceinline__ float wred_sum(float v) {
#pragma unroll
  for (int o = 32; o; o >>= 1) v += __shfl_xor(v, o, 64);
  return v;
}
__device__ __forceinline__ float wred_max(float v) {
#pragma unroll
  for (int o = 32; o; o >>= 1) v = fmaxf(v, __shfl_xor(v, o, 64));
  return v;
}
__device__ __forceinline__ f32x4 mfma16(short8 a, short8 b, f32x4 c) {
  return __builtin_amdgcn_mfma_f32_16x16x32_bf16(a, b, c, 0, 0, 0);
}
__device__ __forceinline__ short8 ldbf(const u16* p) {
  return *reinterpret_cast<const short8*>(p);
}

// ---------------- one fused setup kernel ----------------
// regions: ctx[0,1024) lin[1024,2048) h2aT[2048,2304) logit[2304,7048)
// fc[7048,7176) attb[7176,32264) wc[32264,38408) xemb[38408,38920)
__global__ __launch_bounds__(256) void k_setup(
    const float* __restrict__ ctx_W, u16* __restrict__ ctxWb,
    const float* __restrict__ lin_W, u16* __restrict__ linWb,
    const float* __restrict__ h2a_W, u16* __restrict__ h2aWT,
    const float* __restrict__ logit_W, u16* __restrict__ lWb,
    const float* __restrict__ fc, u16* __restrict__ fcb,
    const float* __restrict__ attf, u16* __restrict__ attb,
    const float* __restrict__ Wih, const float* __restrict__ Whh, u16* __restrict__ Wc,
    const float* __restrict__ emb, const int* __restrict__ seq, u16* __restrict__ Xemb) {
  int blk = blockIdx.x, t = threadIdx.x;
  if (blk >= 2048 && blk < 2304) {
    // h2a transpose: WT[k][j] = W[j][k]  (coalesced read, scattered 2B writes; 0.5MB)
    int i = (blk - 2048) * 256 + t;
    int idx = i * 4;
    int j = idx >> 9, k = idx & 511;
    float4 v = *reinterpret_cast<const float4*>(h2a_W + idx);
    h2aWT[(size_t)(k + 0) * HH + j] = f2bf(v.x);
    h2aWT[(size_t)(k + 1) * HH + j] = f2bf(v.y);
    h2aWT[(size_t)(k + 2) * HH + j] = f2bf(v.z);
    h2aWT[(size_t)(k + 3) * HH + j] = f2bf(v.w);
  } else if (blk < 32264) {
    const float* s; u16* d; int rel;
    if (blk < 1024)      { s = ctx_W;   d = ctxWb; rel = blk; }
    else if (blk < 2048) { s = lin_W;   d = linWb; rel = blk - 1024; }
    else if (blk < 7048) { s = logit_W; d = lWb;   rel = blk - 2304; }
    else if (blk < 7176) { s = fc;      d = fcb;   rel = blk - 7048; }
    else                 { s = attf;    d = attb;  rel = blk - 7176; }
    int i = rel * 256 + t;
    float4 v = reinterpret_cast<const float4*>(s)[i];
    ushort4 o; o.x = f2bf(v.x); o.y = f2bf(v.y); o.z = f2bf(v.z); o.w = f2bf(v.w);
    reinterpret_cast<ushort4*>(d)[i] = o;
  } else if (blk < 38408) {
    int i = (blk - 32264) * 256 + t;
    int idx = i * 4;
    int n = idx / KXX, k = idx - n * KXX;
    const float* p = (k < 2560) ? (Wih + (size_t)n * 2560 + k) : (Whh + (size_t)n * HH + (k - 2560));
    float4 v = *reinterpret_cast<const float4*>(p);
    ushort4 o; o.x = f2bf(v.x); o.y = f2bf(v.y); o.z = f2bf(v.z); o.w = f2bf(v.w);
    reinterpret_cast<ushort4*>(Wc)[i] = o;
  } else {
    int i = (blk - 38408) * 256 + t;
    int idx = i * 4;
    int tt = idx / (BB * HH);
    int r = idx - tt * (BB * HH);
    int b = r / HH, k = r - b * HH;
    int tok = seq[b * 17 + tt];
    float4 v = *reinterpret_cast<const float4*>(emb + (size_t)tok * HH + k);
    ushort4 o; o.x = f2bf(v.x); o.y = f2bf(v.y); o.z = f2bf(v.z); o.w = f2bf(v.w);
    reinterpret_cast<ushort4*>(Xemb)[i] = o;
  }
}

// h0 = c0 = fc @ lin_W^T + lin_b  -> Xh slice 0 (bf16) and c (f32)
__global__ __launch_bounds__(256) void k_h0(const u16* __restrict__ fcb, const u16* __restrict__ linWb,
                                            const float* __restrict__ lin_b,
                                            u16* __restrict__ hb, float* __restrict__ c) {
  int lane = threadIdx.x & 63;
  int m0 = (threadIdx.x >> 6) * 16, n0 = blockIdx.x * 16;
  const u16* xr = fcb + (size_t)(m0 + (lane & 15)) * FF + ((lane >> 4) * 8);
  const u16* wr = linWb + (size_t)(n0 + (lane & 15)) * FF + ((lane >> 4) * 8);
  f32x4 acc = {0.f, 0.f, 0.f, 0.f};
#pragma unroll 8
  for (int kk = 0; kk < 64; ++kk)
    acc = mfma16(ldbf(xr + kk * 32), ldbf(wr + kk * 32), acc);
  int col = n0 + (lane & 15);
  float bias = lin_b[col];
#pragma unroll
  for (int j = 0; j < 4; ++j) {
    int row = m0 + (lane >> 4) * 4 + j;
    float v = acc[j] + bias;
    hb[row * HH + col] = f2bf(v);
    c[row * HH + col] = v;
  }
}

// p_att = att_feats @ ctx_W^T + ctx_b. 128x128 tile (R6/R8-proven, 61us).
__global__ __launch_bounds__(256) void k_patt(const u16* __restrict__ attb,
                                              const u16* __restrict__ ctxWb, const float* __restrict__ ctx_b,
                                              u16* __restrict__ p_att) {
  __shared__ __align__(16) u16 As[128][32];
  __shared__ __align__(16) u16 Bs[128][32];
  int d = blockIdx.x;
  int bid = (d & 7) * 49 + (d >> 3);     // 392 = 8*49, bijective XCD remap
  int mb = bid >> 2, nb = bid & 3;       // 98 x 4
  int m0 = mb * 128, n0 = nb * 128;
  int tid = threadIdx.x;
  int wid = tid >> 6, lane = tid & 63;
  int wr = wid >> 1, wc = wid & 1;
  int ar = lane & 15, ak = (lane >> 4) * 8;
  int rt = tid >> 1, st = tid & 1;
  const u16* agp = attb + (size_t)(m0 + rt) * FF + st * 16;
  const u16* bgp = ctxWb + (size_t)(n0 + rt) * FF + st * 16;

  f32x4 zero = {0.f, 0.f, 0.f, 0.f};
  f32x4 acc[4][4];
#pragma unroll
  for (int i = 0; i < 4; ++i)
#pragma unroll
    for (int j = 0; j < 4; ++j) acc[i][j] = zero;

  for (int ks = 0; ks < 64; ++ks) {
    int k0 = ks * 32;
    short8 a0 = ldbf(agp + k0);
    short8 a1 = ldbf(agp + k0 + 8);
    short8 b0 = ldbf(bgp + k0);
    short8 b1 = ldbf(bgp + k0 + 8);
    __syncthreads();
    *reinterpret_cast<short8*>(&As[rt][st * 16]) = a0;
    *reinterpret_cast<short8*>(&As[rt][st * 16 + 8]) = a1;
    *reinterpret_cast<short8*>(&Bs[rt][st * 16]) = b0;
    *reinterpret_cast<short8*>(&Bs[rt][st * 16 + 8]) = b1;
    __syncthreads();
    short8 af[4], bfr[4];
#pragma unroll
    for (int i = 0; i < 4; ++i)
      af[i] = *reinterpret_cast<const short8*>(&As[wr * 64 + i * 16 + ar][ak]);
#pragma unroll
    for (int j = 0; j < 4; ++j)
      bfr[j] = *reinterpret_cast<const short8*>(&Bs[wc * 64 + j * 16 + ar][ak]);
#pragma unroll
    for (int i = 0; i < 4; ++i)
#pragma unroll
      for (int j = 0; j < 4; ++j)
        acc[i][j] = mfma16(af[i], bfr[j], acc[i][j]);
  }
#pragma unroll
  for (int j = 0; j < 4; ++j) {
    int col = n0 + wc * 64 + j * 16 + ar;
    float bias = ctx_b[col];
#pragma unroll
    for (int i = 0; i < 4; ++i)
#pragma unroll
      for (int q = 0; q < 4; ++q) {
        int row = m0 + wr * 64 + i * 16 + (lane >> 4) * 4 + q;
        p_att[(size_t)row * HH + col] = f2bf(acc[i][j][q] + bias);
      }
  }
}

// ---------------- per-step kernels (3 per step) ----------------
// ae2: one block per b. Phase 1: ah = h @ h2a^T + b via COALESCED GEMV
// (transposed weight: thread j reads WT[k][2j] ushort2, h[k] LDS-broadcast).
// Phase 2: e[l] = alpha . tanh(p_att + ah) + b (wave per l).
// Phase 3: softmax -> w[b][196].  All deps block-local -> legal fusion.
__global__ __launch_bounds__(256) void k_ae2(const u16* __restrict__ Xht, const u16* __restrict__ h2aWT,
                                             const float* __restrict__ h2ab, const u16* __restrict__ p_att,
                                             const float* __restrict__ alphaW, const float* __restrict__ alphab,
                                             float* __restrict__ w) {
  __shared__ float hs[HH];
  __shared__ float ah_s[HH];
  __shared__ float e_s[200];
  __shared__ float red[8];
  int b = blockIdx.x, t = threadIdx.x;
  {
    ushort2 hv = *reinterpret_cast<const ushort2*>(Xht + (size_t)b * HH + t * 2);
    hs[t * 2] = bf2f(hv.x);
    hs[t * 2 + 1] = bf2f(hv.y);
  }
  __syncthreads();
  // phase 1: GEMV, thread t owns j = 2t, 2t+1
  float acc0 = 0.f, acc1 = 0.f;
  const u16* wp = h2aWT + t * 2;
#pragma unroll 8
  for (int k = 0; k < HH; ++k) {
    ushort2 ww = *reinterpret_cast<const ushort2*>(wp + (size_t)k * HH);
    float hk = hs[k];
    acc0 += hk * bf2f(ww.x);
    acc1 += hk * bf2f(ww.y);
  }
  float2 bias2 = *reinterpret_cast<const float2*>(h2ab + t * 2);
  ah_s[2 * t] = acc0 + bias2.x;
  ah_s[2 * t + 1] = acc1 + bias2.y;
  __syncthreads();
  // phase 2: e[l], wave per l
  int wid = t >> 6, lane = t & 63;
  float ahr[8], al[8];
  {
    const float4* ap = reinterpret_cast<const float4*>(&ah_s[lane * 8]);
    float4 A0 = ap[0], A1 = ap[1];
    ahr[0] = A0.x; ahr[1] = A0.y; ahr[2] = A0.z; ahr[3] = A0.w;
    ahr[4] = A1.x; ahr[5] = A1.y; ahr[6] = A1.z; ahr[7] = A1.w;
    const float4* wp2 = reinterpret_cast<const float4*>(alphaW + lane * 8);
    float4 W0 = wp2[0], W1 = wp2[1];
    al[0] = W0.x; al[1] = W0.y; al[2] = W0.z; al[3] = W0.w;
    al[4] = W1.x; al[5] = W1.y; al[6] = W1.z; al[7] = W1.w;
  }
  float ab = alphab[0];
  for (int l = wid; l < LL; l += 4) {
    short8 pa = ldbf(p_att + ((size_t)(b * LL + l)) * HH + lane * 8);
    float s = 0.f;
#pragma unroll
    for (int i = 0; i < 8; ++i)
      s += fast_tanh(bf2f((u16)pa[i]) + ahr[i]) * al[i];
    s = wred_sum(s);
    if (!lane) e_s[l] = s + ab;
  }
  __syncthreads();
  // phase 3: softmax (wave 0) -> w
  if (t < 64) {
    float m = fmaxf(fmaxf(e_s[t], e_s[t + 64]), e_s[t + 128]);
    if (t < 4) m = fmaxf(m, e_s[192 + t]);
    m = wred_max(m);
    float s = __expf(e_s[t] - m) + __expf(e_s[t + 64] - m) + __expf(e_s[t + 128] - m);
    if (t < 4) s += __expf(e_s[192 + t] - m);
    s = wred_sum(s);
    float r = 1.0f / s;
    w[b * 256 + t] = __expf(e_s[t] - m) * r;
    w[b * 256 + t + 64] = __expf(e_s[t + 64] - m) * r;
    w[b * 256 + t + 128] = __expf(e_s[t + 128] - m) * r;
    if (t < 4) w[b * 256 + 192 + t] = __expf(e_s[192 + t] - m) * r;
  }
}

// attR: pure weighted sum (w precomputed). 256 blocks = b(64) x f-chunk(4).
__global__ __launch_bounds__(256) void k_attR(const float* __restrict__ w, const u16* __restrict__ attb,
                                              u16* __restrict__ xatt) {
  __shared__ float w_s[LL];
  __shared__ float part[4][512];
  int b = blockIdx.x >> 2, fc4 = blockIdx.x & 3;
  int t = threadIdx.x, wid = t >> 6, lane = t & 63;
  if (t < LL) w_s[t] = w[b * 256 + t];
  __syncthreads();
  int f0 = fc4 * 512 + lane * 8;
  float a8[8] = {0, 0, 0, 0, 0, 0, 0, 0};
  int l0 = wid * 49;
  const u16* ap = attb + ((size_t)(b * LL + l0)) * FF + f0;
#pragma unroll 7
  for (int l = 0; l < 49; ++l) {
    float wv = w_s[l0 + l];
    short8 av = ldbf(ap);
    ap += FF;
#pragma unroll
    for (int i = 0; i < 8; ++i) a8[i] += wv * bf2f((u16)av[i]);
  }
  float4* pp = reinterpret_cast<float4*>(&part[wid][lane * 8]);
  pp[0] = make_float4(a8[0], a8[1], a8[2], a8[3]);
  pp[1] = make_float4(a8[4], a8[5], a8[6], a8[7]);
  __syncthreads();
  int f = 2 * t;
  float v0 = part[0][f] + part[1][f] + part[2][f] + part[3][f];
  float v1 = part[0][f + 1] + part[1][f + 1] + part[2][f + 1] + part[3][f + 1];
  ushort2 o; o.x = f2bf(v0); o.y = f2bf(v1);
  *reinterpret_cast<ushort2*>(xatt + (size_t)b * FF + fc4 * 512 + f) = o;
}

// gates+LSTM: 128 blocks = jt(32) x mq(4); 4 waves = K-quarters (R5/R6/R8-proven)
__global__ __launch_bounds__(256) void k_gatelstm(const u16* __restrict__ Xemb, const u16* __restrict__ xatt,
                                                  const u16* __restrict__ hb_in, const u16* __restrict__ Wc,
                                                  float* __restrict__ c, u16* __restrict__ hb_out, int tstep) {
  __shared__ float sm[4][4][16][16];
  int jt = blockIdx.x >> 2, mq = blockIdx.x & 3;
  int m0 = mq * 16;
  int lane = threadIdx.x & 63, kq = threadIdx.x >> 6;
  int ar = lane & 15, ak8 = (lane >> 4) * 8;
  int m = m0 + ar;
  int wn = jt * 16 + ar;
  f32x4 zero = {0.f, 0.f, 0.f, 0.f};
  f32x4 acc[4] = {zero, zero, zero, zero};
  const u16* xr0 = Xemb + ((size_t)tstep * BB + m) * HH;
  const u16* xr1 = xatt + (size_t)m * FF;
  const u16* xr2 = hb_in + (size_t)m * HH;

#pragma unroll 4
  for (int kk = 0; kk < 24; ++kk) {
    int k = kq * 768 + kk * 32 + ak8;
    short8 a;
    if (k < 512)       a = ldbf(xr0 + k);
    else if (k < 2560) a = ldbf(xr1 + (k - 512));
    else               a = ldbf(xr2 + (k - 2560));
    short8 bv[4];
#pragma unroll
    for (int g = 0; g < 4; ++g)
      bv[g] = ldbf(Wc + (size_t)(g * 512 + wn) * KXX + k);
#pragma unroll
    for (int g = 0; g < 4; ++g) acc[g] = mfma16(a, bv[g], acc[g]);
  }
#pragma unroll
  for (int g = 0; g < 4; ++g)
#pragma unroll
    for (int q = 0; q < 4; ++q)
      sm[kq][g][(lane >> 4) * 4 + q][ar] = acc[g][q];
  __syncthreads();
  int r = threadIdx.x >> 4, cc = threadIdx.x & 15;
  float gi = sm[0][0][r][cc] + sm[1][0][r][cc] + sm[2][0][r][cc] + sm[3][0][r][cc];
  float gf = sm[0][1][r][cc] + sm[1][1][r][cc] + sm[2][1][r][cc] + sm[3][1][r][cc];
  float gg = sm[0][2][r][cc] + sm[1][2][r][cc] + sm[2][2][r][cc] + sm[3][2][r][cc];
  float go = sm[0][3][r][cc] + sm[1][3][r][cc] + sm[2][3][r][cc] + sm[3][3][r][cc];
  int idx = (m0 + r) * HH + jt * 16 + cc;
  float cn = fast_sig(gf) * c[idx] + fast_sig(gi) * fast_tanh(gg);
  float hn = fast_sig(go) * fast_tanh(cn);
  c[idx] = cn;
  hb_out[idx] = f2bf(hn);
}

// ---------------- deferred logits (writes straight into d_out) ----------------
// logits = XhL[1024,512] @ lWb^T + lb.  128x128 tiles, 600 blocks = 8 m x 75 n
// (N padded to 9600; pad rows finite; cols >= VV skipped on store).
// A-row r = t*64 + b  ->  out row b*TT + t.
__global__ __launch_bounds__(256) void k_logall(const u16* __restrict__ XhL, const u16* __restrict__ lWb,
                                                const float* __restrict__ lb, float* __restrict__ out) {
  __shared__ __align__(16) u16 As[128][32];
  __shared__ __align__(16) u16 Bs[128][32];
  int d = blockIdx.x;
  int mb = d & 7, nb = d >> 3;          // blocks sharing A-panel (mb) land on one XCD
  int m0 = mb * 128, n0 = nb * 128;
  int tid = threadIdx.x;
  int wid = tid >> 6, lane = tid & 63;
  int wr = wid >> 1, wc = wid & 1;
  int ar = lane & 15, ak = (lane >> 4) * 8;
  int rt = tid >> 1, st = tid & 1;
  const u16* agp = XhL + (size_t)(m0 + rt) * HH + st * 16;
  const u16* bgp = lWb + (size_t)(n0 + rt) * HH + st * 16;

  f32x4 zero = {0.f, 0.f, 0.f, 0.f};
  f32x4 acc[4][4];
#pragma unroll
  for (int i = 0; i < 4; ++i)
#pragma unroll
    for (int j = 0; j < 4; ++j) acc[i][j] = zero;

  for (int ks = 0; ks < 16; ++ks) {
    int k0 = ks * 32;
    short8 a0 = ldbf(agp + k0);
    short8 a1 = ldbf(agp + k0 + 8);
    short8 b0 = ldbf(bgp + k0);
    short8 b1 = ldbf(bgp + k0 + 8);
    __syncthreads();
    *reinterpret_cast<short8*>(&As[rt][st * 16]) = a0;
    *reinterpret_cast<short8*>(&As[rt][st * 16 + 8]) = a1;
    *reinterpret_cast<short8*>(&Bs[rt][st * 16]) = b0;
    *reinterpret_cast<short8*>(&Bs[rt][st * 16 + 8]) = b1;
    __syncthreads();
    short8 af[4], bfr[4];
#pragma unroll
    for (int i = 0; i < 4; ++i)
      af[i] = *reinterpret_cast<const short8*>(&As[wr * 64 + i * 16 + ar][ak]);
#pragma unroll
    for (int j = 0; j < 4; ++j)
      bfr[j] = *reinterpret_cast<const short8*>(&Bs[wc * 64 + j * 16 + ar][ak]);
#pragma unroll
    for (int i = 0; i < 4; ++i)
#pragma unroll
      for (int j = 0; j < 4; ++j)
        acc[i][j] = mfma16(af[i], bfr[j], acc[i][j]);
  }
#pragma unroll
  for (int j = 0; j < 4; ++j) {
    int col = n0 + wc * 64 + j * 16 + ar;
    if (col >= VV) continue;
    float bias = lb[col];
#pragma unroll
    for (int i = 0; i < 4; ++i)
#pragma unroll
      for (int q = 0; q < 4; ++q) {
        int row = m0 + wr * 64 + i * 16 + (lane >> 4) * 4 + q;
        int bb = row & 63, ts = row >> 6;
        out[((size_t)(bb * TT + ts)) * VV + col] = acc[i][j][q] + bias;
      }
  }
}

// in-place log-softmax on all 1024 out rows
__global__ __launch_bounds__(256) void k_lsmall(float* __restrict__ out) {
  __shared__ float red[8];
  float* row = out + (size_t)blockIdx.x * VV;
  float4* row4 = reinterpret_cast<float4*>(row);
  int t = threadIdx.x, wid = t >> 6, lane = t & 63;
  float4 v[10];
  float m = -1e30f;
#pragma unroll
  for (int p = 0; p < 10; ++p) {
    int i4 = p * 256 + t;
    if (i4 < VV / 4) {
      v[p] = row4[i4];
      m = fmaxf(m, fmaxf(fmaxf(v[p].x, v[p].y), fmaxf(v[p].z, v[p].w)));
    } else {
      v[p] = make_float4(-1e30f, -1e30f, -1e30f, -1e30f);
    }
  }
  m = wred_max(m);
  if (!lane) red[wid] = m;
  __syncthreads();
  m = fmaxf(fmaxf(red[0], red[1]), fmaxf(red[2], red[3]));
  float s = 0.f;
#pragma unroll
  for (int p = 0; p < 10; ++p)
    s += __expf(v[p].x - m) + __expf(v[p].y - m) + __expf(v[p].z - m) + __expf(v[p].w - m);
  s = wred_sum(s);
  if (!lane) red[4 + wid] = s;
  __syncthreads();
  s = red[4] + red[5] + red[6] + red[7];
  float lse = m + __logf(s);
#pragma unroll
  for (int p = 0; p < 10; ++p) {
    int i4 = p * 256 + t;
    if (i4 < VV / 4)
      row4[i4] = make_float4(v[p].x - lse, v[p].y - lse, v[p].z - lse, v[p].w - lse);
  }
}

// ---------------- host ----------------
extern "C" void kernel_launch(void* const* d_in, const int* in_sizes, int n_in,
                              void* d_out, int out_size, void* d_ws, size_t ws_size,
                              hipStream_t stream) {
  const float* fc      = (const float*)d_in[0];
  const float* attf    = (const float*)d_in[1];
  const int*   seq     = (const int*)d_in[2];
  const float* lin_W   = (const float*)d_in[3];
  const float* lin_b   = (const float*)d_in[4];
  const float* emb     = (const float*)d_in[5];
  const float* Wih     = (const float*)d_in[6];
  const float* Whh     = (const float*)d_in[7];
  const float* ctx_W   = (const float*)d_in[8];
  const float* ctx_b   = (const float*)d_in[9];
  const float* h2a_W   = (const float*)d_in[10];
  const float* h2a_b   = (const float*)d_in[11];
  const float* alpha_W = (const float*)d_in[12];
  const float* alpha_b = (const float*)d_in[13];
  const float* logit_W = (const float*)d_in[14];
  const float* logit_b = (const float*)d_in[15];
  float* out = (float*)d_out;

  char* base = (char*)d_ws;
  size_t off = 0;
  auto alloc = [&](size_t bytes) -> char* {
    off = (off + 255) & ~(size_t)255;
    char* p = base + off;
    off += bytes;
    return p;
  };
  // footprint ~93.6 MiB (< R5-proven 95.7 MiB)
  u16*   p_att  = (u16*)alloc((size_t)MM * HH * 2);
  u16*   ctxWb  = (u16*)alloc((size_t)HH * FF * 2);
  u16*   linWb  = (u16*)alloc((size_t)HH * FF * 2);
  u16*   fcb    = (u16*)alloc((size_t)BB * FF * 2);
  u16*   h2aWT  = (u16*)alloc((size_t)HH * HH * 2);
  u16*   Xemb   = (u16*)alloc((size_t)TT * BB * HH * 2);
  float* c      = (float*)alloc((size_t)BB * HH * 4);
  u16*   Xh     = (u16*)alloc((size_t)(TT + 1) * BB * HH * 2);  // slice 0 = h0
  u16*   xatt   = (u16*)alloc((size_t)BB * FF * 2);
  float* w      = (float*)alloc((size_t)BB * 256 * 4);
  u16*   Wc     = (u16*)alloc((size_t)2048 * KXX * 2);
  u16*   lWb    = (u16*)alloc((size_t)NPAD * HH * 2);
  u16*   attb   = (u16*)alloc((size_t)MM * FF * 2);
  (void)ws_size;

  k_setup<<<38920, 256, 0, stream>>>(ctx_W, ctxWb, lin_W, linWb, h2a_W, h2aWT, logit_W, lWb,
                                     fc, fcb, attf, attb, Wih, Whh, Wc, emb, seq, Xemb);
  k_h0<<<32, 256, 0, stream>>>(fcb, linWb, lin_b, Xh, c);
  k_patt<<<392, 256, 0, stream>>>(attb, ctxWb, ctx_b, p_att);
  k_ae2<<<BB, 256, 0, stream>>>(Xh, h2aWT, h2a_b, p_att, alpha_W, alpha_b, w);

  for (int t = 0; t < TT; ++t) {
    u16* ht  = Xh + (size_t)t * BB * HH;
    u16* htn = Xh + (size_t)(t + 1) * BB * HH;
    k_attR<<<256, 256, 0, stream>>>(w, attb, xatt);
    k_gatelstm<<<128, 256, 0, stream>>>(Xemb, xatt, ht, Wc, c, htn, t);
    if (t < TT - 1)
      k_ae2<<<BB, 256, 0, stream>>>(htn, h2aWT, h2a_b, p_att, alpha_W, alpha_b, w);
  }
  k_logall<<<600, 256, 0, stream>>>(Xh + (size_t)BB * HH, lWb, logit_b, out);
  k_lsmall<<<TT * BB, 256, 0, stream>>>(out);
}

// Round 11
// 878.321 us; speedup vs baseline: 1.7517x; 1.7517x over previous
//
#include <hip/hip_runtime.h>
#include <stdint.h>
#include <stddef.h>

#define BB 64
#define LL 196
#define FF 2048
#define HH 512
#define VV 9488
#define NPAD 9600        // lWb padded rows; pad rows stay finite poison, never stored
#define TT 16
#define KXX 3072         // H + F + H (x' = [xt, att_res, h])
#define MM (BB * LL)     // 12544

typedef short short8 __attribute__((ext_vector_type(8)));
typedef float f32x4 __attribute__((ext_vector_type(4)));
typedef unsigned short u16;

typedef __attribute__((address_space(3))) uint32_t lds_u32_t;
typedef __attribute__((address_space(1))) const uint32_t glb_u32_t;

__device__ __forceinline__ u16 f2bf(float f) {
  uint32_t u = __builtin_bit_cast(uint32_t, f);
  u += 0x7FFFu + ((u >> 16) & 1u);   // RNE
  return (u16)(u >> 16);
}
__device__ __forceinline__ float bf2f(u16 s) {
  return __builtin_bit_cast(float, ((uint32_t)s) << 16);
}
__device__ __forceinline__ float fast_tanh(float x) {
  return 1.0f - 2.0f / (1.0f + __expf(2.0f * x));
}
__device__ __forceinline__ float fast_sig(float x) {
  return 1.0f / (1.0f + __expf(-x));
}
__device__ __forceinline__ float wred_sum(float v) {
#pragma unroll
  for (int o = 32; o; o >>= 1) v += __shfl_xor(v, o, 64);
  return v;
}
__device__ __forceinline__ float wred_max(float v) {
#pragma unroll
  for (int o = 32; o; o >>= 1) v = fmaxf(v, __shfl_xor(v, o, 64));
  return v;
}
__device__ __forceinline__ f32x4 mfma16(short8 a, short8 b, f32x4 c) {
  return __builtin_amdgcn_mfma_f32_16x16x32_bf16(a, b, c, 0, 0, 0);
}
__device__ __forceinline__ short8 ldbf(const u16* p) {
  return *reinterpret_cast<const short8*>(p);
}
// async global->LDS, 16B per lane; lds addr must be wave-base + lane*16 (linear)
__device__ __forceinline__ void gload16(const u16* g, u16* l) {
  __builtin_amdgcn_global_load_lds((glb_u32_t*)g, (lds_u32_t*)l, 16, 0, 0);
}

// ---------------- one fused setup kernel (measured 67us) ----------------
// regions: ctx[0,1024) lin[1024,2048) h2a[2048,2304) logit[2304,7048)
// fc[7048,7176) attb[7176,32264) wc[32264,38408) xemb[38408,38920)
__global__ __launch_bounds__(256) void k_setup(
    const float* __restrict__ ctx_W, u16* __restrict__ ctxWb,
    const float* __restrict__ lin_W, u16* __restrict__ linWb,
    const float* __restrict__ h2a_W, u16* __restrict__ h2aWb,
    const float* __restrict__ logit_W, u16* __restrict__ lWb,
    const float* __restrict__ fc, u16* __restrict__ fcb,
    const float* __restrict__ attf, u16* __restrict__ attb,
    const float* __restrict__ Wih, const float* __restrict__ Whh, u16* __restrict__ Wc,
    const float* __restrict__ emb, const int* __restrict__ seq, u16* __restrict__ Xemb) {
  int blk = blockIdx.x, t = threadIdx.x;
  if (blk < 32264) {
    const float* s; u16* d; int rel;
    if (blk < 1024)      { s = ctx_W;   d = ctxWb; rel = blk; }
    else if (blk < 2048) { s = lin_W;   d = linWb; rel = blk - 1024; }
    else if (blk < 2304) { s = h2a_W;   d = h2aWb; rel = blk - 2048; }
    else if (blk < 7048) { s = logit_W; d = lWb;   rel = blk - 2304; }
    else if (blk < 7176) { s = fc;      d = fcb;   rel = blk - 7048; }
    else                 { s = attf;    d = attb;  rel = blk - 7176; }
    int i = rel * 256 + t;
    float4 v = reinterpret_cast<const float4*>(s)[i];
    ushort4 o; o.x = f2bf(v.x); o.y = f2bf(v.y); o.z = f2bf(v.z); o.w = f2bf(v.w);
    reinterpret_cast<ushort4*>(d)[i] = o;
  } else if (blk < 38408) {
    int i = (blk - 32264) * 256 + t;
    int idx = i * 4;
    int n = idx / KXX, k = idx - n * KXX;
    const float* p = (k < 2560) ? (Wih + (size_t)n * 2560 + k) : (Whh + (size_t)n * HH + (k - 2560));
    float4 v = *reinterpret_cast<const float4*>(p);
    ushort4 o; o.x = f2bf(v.x); o.y = f2bf(v.y); o.z = f2bf(v.z); o.w = f2bf(v.w);
    reinterpret_cast<ushort4*>(Wc)[i] = o;
  } else {
    int i = (blk - 38408) * 256 + t;
    int idx = i * 4;
    int tt = idx / (BB * HH);
    int r = idx - tt * (BB * HH);
    int b = r / HH, k = r - b * HH;
    int tok = seq[b * 17 + tt];
    float4 v = *reinterpret_cast<const float4*>(emb + (size_t)tok * HH + k);
    ushort4 o; o.x = f2bf(v.x); o.y = f2bf(v.y); o.z = f2bf(v.z); o.w = f2bf(v.w);
    reinterpret_cast<ushort4*>(Xemb)[i] = o;
  }
}

// h0 = c0 = fc @ lin_W^T + lin_b
__global__ __launch_bounds__(256) void k_h0(const u16* __restrict__ fcb, const u16* __restrict__ linWb,
                                            const float* __restrict__ lin_b,
                                            u16* __restrict__ hb, float* __restrict__ c) {
  int lane = threadIdx.x & 63;
  int m0 = (threadIdx.x >> 6) * 16, n0 = blockIdx.x * 16;
  const u16* xr = fcb + (size_t)(m0 + (lane & 15)) * FF + ((lane >> 4) * 8);
  const u16* wr = linWb + (size_t)(n0 + (lane & 15)) * FF + ((lane >> 4) * 8);
  f32x4 acc = {0.f, 0.f, 0.f, 0.f};
#pragma unroll 8
  for (int kk = 0; kk < 64; ++kk)
    acc = mfma16(ldbf(xr + kk * 32), ldbf(wr + kk * 32), acc);
  int col = n0 + (lane & 15);
  float bias = lin_b[col];
#pragma unroll
  for (int j = 0; j < 4; ++j) {
    int row = m0 + (lane >> 4) * 4 + j;
    float v = acc[j] + bias;
    hb[row * HH + col] = f2bf(v);
    c[row * HH + col] = v;
  }
}

// p_att = att_feats @ ctx_W^T + ctx_b. 128x128 tile; XCD remap;
// staging via global_load_lds width=16 (m97 pattern: no VGPR round-trip).
__global__ __launch_bounds__(256) void k_patt(const u16* __restrict__ attb,
                                              const u16* __restrict__ ctxWb, const float* __restrict__ ctx_b,
                                              u16* __restrict__ p_att) {
  __shared__ __align__(16) u16 As[128][32];
  __shared__ __align__(16) u16 Bs[128][32];
  int d = blockIdx.x;
  int bid = (d & 7) * 49 + (d >> 3);     // 392 = 8*49, bijective XCD remap
  int mb = bid >> 2, nb = bid & 3;       // 98 x 4
  int m0 = mb * 128, n0 = nb * 128;
  int tid = threadIdx.x;
  int wid = tid >> 6, lane = tid & 63;
  int wr = wid >> 1, wc = wid & 1;
  int ar = lane & 15, ak = (lane >> 4) * 8;
  // staging: thread covers LDS row tid>>2 (half0) / +64 (half1), seg tid&3.
  // lds addr = tid*16B = wave-base + lane*16  (linear, HW-constraint OK)
  const u16* ga = attb + (size_t)(m0 + (tid >> 2)) * FF + (tid & 3) * 8;
  const u16* gb = ctxWb + (size_t)(n0 + (tid >> 2)) * FF + (tid & 3) * 8;
  u16* la0 = &As[0][0] + tid * 8;
  u16* la1 = &As[64][0] + tid * 8;
  u16* lb0 = &Bs[0][0] + tid * 8;
  u16* lb1 = &Bs[64][0] + tid * 8;

  f32x4 zero = {0.f, 0.f, 0.f, 0.f};
  f32x4 acc[4][4];
#pragma unroll
  for (int i = 0; i < 4; ++i)
#pragma unroll
    for (int j = 0; j < 4; ++j) acc[i][j] = zero;

  for (int ks = 0; ks < 64; ++ks) {
    int k0 = ks * 32;
    __syncthreads();                 // all waves done reading prev tile
    gload16(ga + k0, la0);
    gload16(ga + k0 + (size_t)64 * FF, la1);
    gload16(gb + k0, lb0);
    gload16(gb + k0 + (size_t)64 * FF, lb1);
    __syncthreads();                 // barrier drain (vmcnt 0) -> LDS ready
    short8 af[4], bfr[4];
#pragma unroll
    for (int i = 0; i < 4; ++i)
      af[i] = *reinterpret_cast<const short8*>(&As[wr * 64 + i * 16 + ar][ak]);
#pragma unroll
    for (int j = 0; j < 4; ++j)
      bfr[j] = *reinterpret_cast<const short8*>(&Bs[wc * 64 + j * 16 + ar][ak]);
#pragma unroll
    for (int i = 0; i < 4; ++i)
#pragma unroll
      for (int j = 0; j < 4; ++j)
        acc[i][j] = mfma16(af[i], bfr[j], acc[i][j]);
  }
#pragma unroll
  for (int j = 0; j < 4; ++j) {
    int col = n0 + wc * 64 + j * 16 + ar;
    float bias = ctx_b[col];
#pragma unroll
    for (int i = 0; i < 4; ++i)
#pragma unroll
      for (int q = 0; q < 4; ++q) {
        int row = m0 + wr * 64 + i * 16 + (lane >> 4) * 4 + q;
        p_att[(size_t)row * HH + col] = f2bf(acc[i][j][q] + bias);
      }
  }
}

// ---------------- per-step device bodies ----------------
__device__ __forceinline__ void dev_atth(int nt, const u16* __restrict__ hb, const u16* __restrict__ h2aWb,
                                         const float* __restrict__ h2ab, float* __restrict__ ah) {
  int lane = threadIdx.x & 63;
  int m0 = (threadIdx.x >> 6) * 16, n0 = nt * 16;
  int ak = (lane >> 4) * 8;
  const u16* xr = hb + (size_t)(m0 + (lane & 15)) * HH + ak;
  const u16* wr = h2aWb + (size_t)(n0 + (lane & 15)) * HH + ak;
  f32x4 acc = {0.f, 0.f, 0.f, 0.f};
#pragma unroll
  for (int kk = 0; kk < 16; ++kk)
    acc = mfma16(ldbf(xr + kk * 32), ldbf(wr + kk * 32), acc);
  int col = n0 + (lane & 15);
  float bias = h2ab[col];
#pragma unroll
  for (int j = 0; j < 4; ++j)
    ah[(size_t)(m0 + (lane >> 4) * 4 + j) * HH + col] = acc[j] + bias;
}

__device__ __forceinline__ void dev_e(int bid4, const u16* __restrict__ p_att, const float* __restrict__ ah,
                                      const float* __restrict__ alphaW, const float* __restrict__ alphab,
                                      float* __restrict__ e) {
  int gw = bid4 * 4 + (threadIdx.x >> 6);   // [0, 12544)
  int lane = threadIdx.x & 63;
  int b = gw / LL, l = gw - b * LL;
  short8 pa = ldbf(p_att + (size_t)gw * HH + lane * 8);
  const float4* ap = reinterpret_cast<const float4*>(ah + (size_t)b * HH + lane * 8);
  float4 a0 = ap[0], a1 = ap[1];
  const float4* wp = reinterpret_cast<const float4*>(alphaW + lane * 8);
  float4 w0 = wp[0], w1 = wp[1];
  float s = fast_tanh(bf2f((u16)pa[0]) + a0.x) * w0.x
          + fast_tanh(bf2f((u16)pa[1]) + a0.y) * w0.y
          + fast_tanh(bf2f((u16)pa[2]) + a0.z) * w0.z
          + fast_tanh(bf2f((u16)pa[3]) + a0.w) * w0.w
          + fast_tanh(bf2f((u16)pa[4]) + a1.x) * w1.x
          + fast_tanh(bf2f((u16)pa[5]) + a1.y) * w1.y
          + fast_tanh(bf2f((u16)pa[6]) + a1.z) * w1.z
          + fast_tanh(bf2f((u16)pa[7]) + a1.w) * w1.w;
  s = wred_sum(s);
  if (!lane) e[b * 256 + l] = s + alphab[0];
}

// 2 n-tiles per wave: shared A-frag, 2 independent MFMA chains (ILP x2).
__device__ __forceinline__ void dev_logits2(int nt2, const u16* __restrict__ hb, const u16* __restrict__ lWb,
                                            const float* __restrict__ lb, float* __restrict__ logits) {
  int lane = threadIdx.x & 63;
  int m0 = (threadIdx.x >> 6) * 16, n0 = nt2 * 32;
  int ak = (lane >> 4) * 8;
  const u16* xr = hb + (size_t)(m0 + (lane & 15)) * HH + ak;
  int wn0 = n0 + (lane & 15);         // row < 9488 always (n0 <= 9472)
  const u16* b0 = lWb + (size_t)wn0 * HH + ak;
  const u16* b1 = b0 + (size_t)16 * HH;   // rows < 9504 <= NPAD alloc
  f32x4 acc0 = {0.f, 0.f, 0.f, 0.f};
  f32x4 acc1 = {0.f, 0.f, 0.f, 0.f};
#pragma unroll
  for (int kk = 0; kk < 16; ++kk) {
    short8 a = ldbf(xr + kk * 32);
    acc0 = mfma16(a, ldbf(b0 + kk * 32), acc0);
    acc1 = mfma16(a, ldbf(b1 + kk * 32), acc1);
  }
  int col0 = n0 + (lane & 15);        // always < VV
  int col1 = col0 + 16;               // may exceed VV on last tile
  float bias0 = lb[col0];
  float bias1 = (col1 < VV) ? lb[col1] : 0.f;
#pragma unroll
  for (int j = 0; j < 4; ++j) {
    size_t row = (size_t)(m0 + (lane >> 4) * 4 + j) * VV;
    logits[row + col0] = acc0[j] + bias0;
    if (col1 < VV) logits[row + col1] = acc1[j] + bias1;
  }
}

__device__ __forceinline__ void dev_lsm(float* red, int b, const float* __restrict__ logits,
                                        float* __restrict__ out, int tstep) {
  const float4* row4 = reinterpret_cast<const float4*>(logits + (size_t)b * VV);
  int t = threadIdx.x, wid = t >> 6, lane = t & 63;
  float4 v[10];
  float m = -1e30f;
#pragma unroll
  for (int p = 0; p < 10; ++p) {
    int i4 = p * 256 + t;
    if (i4 < VV / 4) {
      v[p] = row4[i4];
      m = fmaxf(m, fmaxf(fmaxf(v[p].x, v[p].y), fmaxf(v[p].z, v[p].w)));
    } else {
      v[p] = make_float4(-1e30f, -1e30f, -1e30f, -1e30f);
    }
  }
  m = wred_max(m);
  if (!lane) red[wid] = m;
  __syncthreads();
  m = fmaxf(fmaxf(red[0], red[1]), fmaxf(red[2], red[3]));
  float s = 0.f;
#pragma unroll
  for (int p = 0; p < 10; ++p)
    s += __expf(v[p].x - m) + __expf(v[p].y - m) + __expf(v[p].z - m) + __expf(v[p].w - m);
  s = wred_sum(s);
  if (!lane) red[4 + wid] = s;
  __syncthreads();
  s = red[4] + red[5] + red[6] + red[7];
  float lse = m + __logf(s);
  float4* orow = reinterpret_cast<float4*>(out + ((size_t)b * TT + tstep) * VV);
#pragma unroll
  for (int p = 0; p < 10; ++p) {
    int i4 = p * 256 + t;
    if (i4 < VV / 4)
      orow[i4] = make_float4(v[p].x - lse, v[p].y - lse, v[p].z - lse, v[p].w - lse);
  }
}

// ---------------- per-step kernels (R8 structure: 4 per step) ----------------
__global__ __launch_bounds__(256) void k_atth(const u16* __restrict__ hb, const u16* __restrict__ h2aWb,
                                              const float* __restrict__ h2ab, float* __restrict__ ah) {
  dev_atth(blockIdx.x, hb, h2aWb, h2ab, ah);
}
__global__ __launch_bounds__(256) void k_e(const u16* __restrict__ p_att, const float* __restrict__ ah,
                                           const float* __restrict__ alphaW, const float* __restrict__ alphab,
                                           float* __restrict__ e) {
  dev_e(blockIdx.x, p_att, ah, alphaW, alphab, e);
}

// attR: softmax(e[b,:]) per block (redundant x4, cheap) then weighted sum.
// 256 blocks = b(64) x f-chunk(4) of 512 feats (R8-proven body).
__global__ __launch_bounds__(256) void k_attR(const float* __restrict__ e, const u16* __restrict__ attb,
                                              u16* __restrict__ xatt) {
  __shared__ float w_s[LL];
  __shared__ float red[8];
  __shared__ float part[4][512];
  int b = blockIdx.x >> 2, fc4 = blockIdx.x & 3;
  int t = threadIdx.x, wid = t >> 6, lane = t & 63;
  float ev = (t < LL) ? e[b * 256 + t] : -1e30f;
  float m = wred_max(ev);
  if (!lane) red[wid] = m;
  __syncthreads();
  m = fmaxf(fmaxf(red[0], red[1]), fmaxf(red[2], red[3]));
  float ex = __expf(ev - m);
  float s = wred_sum(ex);
  if (!lane) red[4 + wid] = s;
  __syncthreads();
  s = red[4] + red[5] + red[6] + red[7];
  if (t < LL) w_s[t] = ex / s;
  __syncthreads();

  int f0 = fc4 * 512 + lane * 8;
  float a8[8] = {0, 0, 0, 0, 0, 0, 0, 0};
  int l0 = wid * 49;
  const u16* ap = attb + ((size_t)(b * LL + l0)) * FF + f0;
#pragma unroll 7
  for (int l = 0; l < 49; ++l) {
    float w = w_s[l0 + l];
    short8 av = ldbf(ap);
    ap += FF;
#pragma unroll
    for (int i = 0; i < 8; ++i) a8[i] += w * bf2f((u16)av[i]);
  }
  float4* pp = reinterpret_cast<float4*>(&part[wid][lane * 8]);
  pp[0] = make_float4(a8[0], a8[1], a8[2], a8[3]);
  pp[1] = make_float4(a8[4], a8[5], a8[6], a8[7]);
  __syncthreads();
  int f = 2 * t;
  float v0 = part[0][f] + part[1][f] + part[2][f] + part[3][f];
  float v1 = part[0][f + 1] + part[1][f + 1] + part[2][f + 1] + part[3][f + 1];
  ushort2 o; o.x = f2bf(v0); o.y = f2bf(v1);
  *reinterpret_cast<ushort2*>(xatt + (size_t)b * FF + fc4 * 512 + f) = o;
}

// gates+LSTM: 128 blocks = jt(32) x mq(4); 4 waves = K-quarters (R5/R6/R8-proven)
__global__ __launch_bounds__(256) void k_gatelstm(const u16* __restrict__ Xemb, const u16* __restrict__ xatt,
                                                  const u16* __restrict__ hb_in, const u16* __restrict__ Wc,
                                                  float* __restrict__ c, u16* __restrict__ hb_out, int tstep) {
  __shared__ float sm[4][4][16][16];
  int jt = blockIdx.x >> 2, mq = blockIdx.x & 3;
  int m0 = mq * 16;
  int lane = threadIdx.x & 63, kq = threadIdx.x >> 6;
  int ar = lane & 15, ak8 = (lane >> 4) * 8;
  int m = m0 + ar;
  int wn = jt * 16 + ar;
  f32x4 zero = {0.f, 0.f, 0.f, 0.f};
  f32x4 acc[4] = {zero, zero, zero, zero};
  const u16* xr0 = Xemb + ((size_t)tstep * BB + m) * HH;
  const u16* xr1 = xatt + (size_t)m * FF;
  const u16* xr2 = hb_in + (size_t)m * HH;

#pragma unroll 4
  for (int kk = 0; kk < 24; ++kk) {
    int k = kq * 768 + kk * 32 + ak8;
    short8 a;
    if (k < 512)       a = ldbf(xr0 + k);
    else if (k < 2560) a = ldbf(xr1 + (k - 512));
    else               a = ldbf(xr2 + (k - 2560));
    short8 bv[4];
#pragma unroll
    for (int g = 0; g < 4; ++g)
      bv[g] = ldbf(Wc + (size_t)(g * 512 + wn) * KXX + k);
#pragma unroll
    for (int g = 0; g < 4; ++g) acc[g] = mfma16(a, bv[g], acc[g]);
  }
#pragma unroll
  for (int g = 0; g < 4; ++g)
#pragma unroll
    for (int q = 0; q < 4; ++q)
      sm[kq][g][(lane >> 4) * 4 + q][ar] = acc[g][q];
  __syncthreads();
  int r = threadIdx.x >> 4, cc = threadIdx.x & 15;
  float gi = sm[0][0][r][cc] + sm[1][0][r][cc] + sm[2][0][r][cc] + sm[3][0][r][cc];
  float gf = sm[0][1][r][cc] + sm[1][1][r][cc] + sm[2][1][r][cc] + sm[3][1][r][cc];
  float gg = sm[0][2][r][cc] + sm[1][2][r][cc] + sm[2][2][r][cc] + sm[3][2][r][cc];
  float go = sm[0][3][r][cc] + sm[1][3][r][cc] + sm[2][3][r][cc] + sm[3][3][r][cc];
  int idx = (m0 + r) * HH + jt * 16 + cc;
  float cn = fast_sig(gf) * c[idx] + fast_sig(gi) * fast_tanh(gg);
  float hn = fast_sig(go) * fast_tanh(cn);
  c[idx] = cn;
  hb_out[idx] = f2bf(hn);
}

// logits(t) [0..296] (2 tiles/wave) + atth(t+1) rider [297..328]
__global__ __launch_bounds__(256) void k_logatt(const u16* __restrict__ hb, const u16* __restrict__ lWb,
                                                const float* __restrict__ lb, float* __restrict__ logits,
                                                const u16* __restrict__ h2aWb, const float* __restrict__ h2ab,
                                                float* __restrict__ ah, int do_next) {
  int bid = blockIdx.x;
  if (bid < 297) dev_logits2(bid, hb, lWb, lb, logits);
  else if (do_next) dev_atth(bid - 297, hb, h2aWb, h2ab, ah);
}
// lsm(t) [0..63] + e(t+1) rider [64..3199]
__global__ __launch_bounds__(256) void k_lsme(const float* __restrict__ logits, float* __restrict__ out,
                                              int tstep, const u16* __restrict__ p_att,
                                              const float* __restrict__ ah, const float* __restrict__ alphaW,
                                              const float* __restrict__ alphab, float* __restrict__ e,
                                              int do_next) {
  __shared__ float red[8];
  int bid = blockIdx.x;
  if (bid < 64) dev_lsm(red, bid, logits, out, tstep);
  else if (do_next) dev_e(bid - 64, p_att, ah, alphaW, alphab, e);
}

// ---------------- host ----------------
extern "C" void kernel_launch(void* const* d_in, const int* in_sizes, int n_in,
                              void* d_out, int out_size, void* d_ws, size_t ws_size,
                              hipStream_t stream) {
  const float* fc      = (const float*)d_in[0];
  const float* attf    = (const float*)d_in[1];
  const int*   seq     = (const int*)d_in[2];
  const float* lin_W   = (const float*)d_in[3];
  const float* lin_b   = (const float*)d_in[4];
  const float* emb     = (const float*)d_in[5];
  const float* Wih     = (const float*)d_in[6];
  const float* Whh     = (const float*)d_in[7];
  const float* ctx_W   = (const float*)d_in[8];
  const float* ctx_b   = (const float*)d_in[9];
  const float* h2a_W   = (const float*)d_in[10];
  const float* h2a_b   = (const float*)d_in[11];
  const float* alpha_W = (const float*)d_in[12];
  const float* alpha_b = (const float*)d_in[13];
  const float* logit_W = (const float*)d_in[14];
  const float* logit_b = (const float*)d_in[15];
  float* out = (float*)d_out;

  char* base = (char*)d_ws;
  size_t off = 0;
  auto alloc = [&](size_t bytes) -> char* {
    off = (off + 255) & ~(size_t)255;
    char* p = base + off;
    off += bytes;
    return p;
  };
  // footprint ~91.6 MiB (R5/R6/R8-proven to fit)
  u16*   p_att  = (u16*)alloc((size_t)MM * HH * 2);
  u16*   ctxWb  = (u16*)alloc((size_t)HH * FF * 2);
  u16*   linWb  = (u16*)alloc((size_t)HH * FF * 2);
  u16*   fcb    = (u16*)alloc((size_t)BB * FF * 2);
  u16*   h2aWb  = (u16*)alloc((size_t)HH * HH * 2);
  u16*   Xemb   = (u16*)alloc((size_t)TT * BB * HH * 2);
  float* c      = (float*)alloc((size_t)BB * HH * 4);
  u16*   hbA    = (u16*)alloc((size_t)BB * HH * 2);
  u16*   hbB    = (u16*)alloc((size_t)BB * HH * 2);
  u16*   xatt   = (u16*)alloc((size_t)BB * FF * 2);
  float* eb     = (float*)alloc((size_t)BB * 256 * 4);
  float* ah     = (float*)alloc((size_t)BB * HH * 4);
  float* logits = (float*)alloc((size_t)BB * VV * 4);
  u16*   Wc     = (u16*)alloc((size_t)2048 * KXX * 2);
  u16*   lWb    = (u16*)alloc((size_t)NPAD * HH * 2);   // pad rows: finite poison, never stored
  u16*   attb   = (u16*)alloc((size_t)MM * FF * 2);
  (void)ws_size;

  k_setup<<<38920, 256, 0, stream>>>(ctx_W, ctxWb, lin_W, linWb, h2a_W, h2aWb, logit_W, lWb,
                                     fc, fcb, attf, attb, Wih, Whh, Wc, emb, seq, Xemb);
  k_h0<<<32, 256, 0, stream>>>(fcb, linWb, lin_b, hbA, c);
  k_patt<<<392, 256, 0, stream>>>(attb, ctxWb, ctx_b, p_att);

  // prologue: ah(0), e(0)
  k_atth<<<32, 256, 0, stream>>>(hbA, h2aWb, h2a_b, ah);
  k_e<<<MM / 4, 256, 0, stream>>>(p_att, ah, alpha_W, alpha_b, eb);

  for (int t = 0; t < TT; ++t) {
    u16* hb_in  = (t & 1) ? hbB : hbA;
    u16* hb_out = (t & 1) ? hbA : hbB;
    int more = (t < TT - 1) ? 1 : 0;
    k_attR<<<256, 256, 0, stream>>>(eb, attb, xatt);
    k_gatelstm<<<128, 256, 0, stream>>>(Xemb, xatt, hb_in, Wc, c, hb_out, t);
    k_logatt<<<329, 256, 0, stream>>>(hb_out, lWb, logit_b, logits, h2aWb, h2a_b, ah, more);
    k_lsme<<<64 + MM / 4, 256, 0, stream>>>(logits, out, t, p_att, ah, alpha_W, alpha_b, eb, more);
  }
}